// Round 1
// baseline (923.774 us; speedup 1.0000x reference)
//
#include <hip/hip_runtime.h>

// MPS chain: v_new[b,r] = sum_{l,i} v[b,l] * W[l,i,r] * x[b,k,i], 62 steps, D=128.
// fp32 vector baseline. Block = 256 thr = 32-batch tile x 128 r.
// Thread tile: 4 batch x 4 r x 2 i accumulators (32 regs).

#define D       128
#define BT      32      // batch tile per block
#define NMID    62
#define NSITES  64

__global__ __launch_bounds__(256, 2) void mps_chain_kernel(
    const float* __restrict__ x,    // [B, 64, 2]
    const float* __restrict__ wf,   // [2, 2]  (i, r)
    const float* __restrict__ wm,   // [62, 128, 2, 128]  (k, l, i, r)
    const float* __restrict__ wl,   // [2, 2]  (l, i)
    float* __restrict__ out)        // [B]
{
    __shared__ float vbuf[2][D][BT];          // ping-pong chain state, [l][b]
    __shared__ float xs_lds[BT][126];         // x sites 1..63 per local batch

    const int tid = threadIdx.x;
    const int rg  = tid >> 3;       // 0..31 -> r0 = rg*4
    const int bg  = tid & 7;        // 0..7  -> b0 = bg*4
    const int r0  = rg * 4;
    const int b0  = bg * 4;
    const int bbase = blockIdx.x * BT;

    // ---- stage x (sites 1..63) into LDS ----
    for (int idx = tid; idx < BT * 126; idx += 256) {
        int b = idx / 126, j = idx % 126;
        xs_lds[b][j] = x[(size_t)(bbase + b) * 128 + 2 + j];
    }

    // ---- init v from first site: v[r] = wf[0*2+r]*x0 + wf[1*2+r]*x1, r<2 ----
    const float wf00 = wf[0], wf01 = wf[1], wf10 = wf[2], wf11 = wf[3];
    for (int idx = tid; idx < D * BT; idx += 256) {
        int l = idx / BT, b = idx % BT;
        float val = 0.0f;
        if (l < 2) {
            float x0 = x[(size_t)(bbase + b) * 128 + 0];
            float x1 = x[(size_t)(bbase + b) * 128 + 1];
            val = (l == 0) ? (wf00 * x0 + wf10 * x1)
                           : (wf01 * x0 + wf11 * x1);
        }
        vbuf[0][l][b] = val;
    }
    __syncthreads();

    int cur = 0;
    for (int k = 0; k < NMID; ++k) {
        const float* __restrict__ Wk = wm + (size_t)k * (2 * D * D);

        float acc0[4][4], acc1[4][4];
        #pragma unroll
        for (int bb = 0; bb < 4; ++bb)
            #pragma unroll
            for (int rr = 0; rr < 4; ++rr) { acc0[bb][rr] = 0.0f; acc1[bb][rr] = 0.0f; }

        #pragma unroll 4
        for (int l = 0; l < D; ++l) {
            float4 vv = *reinterpret_cast<const float4*>(&vbuf[cur][l][b0]);
            float4 w0 = *reinterpret_cast<const float4*>(&Wk[(size_t)(2 * l) * D + r0]);
            float4 w1 = *reinterpret_cast<const float4*>(&Wk[(size_t)(2 * l + 1) * D + r0]);
            float va[4]  = { vv.x, vv.y, vv.z, vv.w };
            float w0a[4] = { w0.x, w0.y, w0.z, w0.w };
            float w1a[4] = { w1.x, w1.y, w1.z, w1.w };
            #pragma unroll
            for (int bb = 0; bb < 4; ++bb) {
                #pragma unroll
                for (int rr = 0; rr < 4; ++rr) {
                    acc0[bb][rr] = fmaf(va[bb], w0a[rr], acc0[bb][rr]);
                    acc1[bb][rr] = fmaf(va[bb], w1a[rr], acc1[bb][rr]);
                }
            }
        }

        // combine with x and write v_new into the other buffer
        const int nxt = cur ^ 1;
        float vn[4][4];
        #pragma unroll
        for (int bb = 0; bb < 4; ++bb) {
            float xx0 = xs_lds[b0 + bb][2 * k + 0];
            float xx1 = xs_lds[b0 + bb][2 * k + 1];
            #pragma unroll
            for (int rr = 0; rr < 4; ++rr)
                vn[bb][rr] = xx0 * acc0[bb][rr] + xx1 * acc1[bb][rr];
        }
        #pragma unroll
        for (int rr = 0; rr < 4; ++rr) {
            float4 wv = make_float4(vn[0][rr], vn[1][rr], vn[2][rr], vn[3][rr]);
            *reinterpret_cast<float4*>(&vbuf[nxt][r0 + rr][b0]) = wv;
        }
        cur = nxt;
        __syncthreads();
    }

    // ---- finale: out[b] = sum_{l<2} v[b,l] * (wl[l,0]*x0 + wl[l,1]*x1), site 63 ----
    if (rg == 0) {
        const float wl00 = wl[0], wl01 = wl[1], wl10 = wl[2], wl11 = wl[3];
        #pragma unroll
        for (int bb = 0; bb < 4; ++bb) {
            int b = b0 + bb;
            float v0 = vbuf[cur][0][b];
            float v1 = vbuf[cur][1][b];
            float xx0 = xs_lds[b][124];
            float xx1 = xs_lds[b][125];
            out[bbase + b] = v0 * (wl00 * xx0 + wl01 * xx1)
                           + v1 * (wl10 * xx0 + wl11 * xx1);
        }
    }
}

extern "C" void kernel_launch(void* const* d_in, const int* in_sizes, int n_in,
                              void* d_out, int out_size, void* d_ws, size_t ws_size,
                              hipStream_t stream) {
    const float* x  = (const float*)d_in[0];
    const float* wf = (const float*)d_in[1];
    const float* wm = (const float*)d_in[2];
    const float* wl = (const float*)d_in[3];
    float* out = (float*)d_out;

    const int BATCH = 16384;
    dim3 grid(BATCH / BT), block(256);
    hipLaunchKernelGGL(mps_chain_kernel, grid, block, 0, stream,
                       x, wf, wm, wl, out);
}

// Round 3
// 278.017 us; speedup vs baseline: 3.3227x; 3.3227x over previous
//
#include <hip/hip_runtime.h>
#include <stdint.h>

#define NMID 62
#define NBATCH 16384

typedef __attribute__((ext_vector_type(8))) short short8;
typedef __attribute__((ext_vector_type(4))) float f32x4;
typedef __attribute__((ext_vector_type(4))) unsigned int u32x4;

__device__ __forceinline__ unsigned short f32_to_bf16_rne(float f) {
    unsigned u = __builtin_bit_cast(unsigned, f);
    u += 0x7fffu + ((u >> 16) & 1u);
    return (unsigned short)(u >> 16);
}
__device__ __forceinline__ float bf16_to_f32(unsigned short h) {
    unsigned u = ((unsigned)h) << 16;
    return __builtin_bit_cast(float, u);
}

// ---- prep: pack W[62,128,2,128] fp32 into MFMA B-fragment order, bf16 hi/lo ----
// frag addr (u32x4 units): f = ((((k*2+i)*8 + nt)*4 + kt)*2 + hl)*64 + lane.
// B-frag slot (g=lane>>4, j): l = kt*32 + g*8 + j, col r = nt*16 + (lane&15).
__global__ void mps_pack_w(const float* __restrict__ wm, u32x4* __restrict__ wpk) {
    int t = blockIdx.x * blockDim.x + threadIdx.x;
    if (t >= 124 * 8 * 4 * 64) return;
    int lane = t & 63;
    int kt = (t >> 6) & 3;
    int nt = (t >> 8) & 7;
    int k2 = t >> 11;                 // k*2 + i
    int k = k2 >> 1, i = k2 & 1;
    int r = nt * 16 + (lane & 15);
    int lbase = kt * 32 + (lane >> 4) * 8;
    unsigned hw[4], lw[4];
    #pragma unroll
    for (int d = 0; d < 4; ++d) {
        unsigned hword = 0, lword = 0;
        #pragma unroll
        for (int e = 0; e < 2; ++e) {
            int l = lbase + d * 2 + e;
            float w = wm[((size_t)k * 128 + l) * 256 + i * 128 + r];
            unsigned short h = f32_to_bf16_rne(w);
            float rem = w - bf16_to_f32(h);
            unsigned short lo = f32_to_bf16_rne(rem);
            hword |= ((unsigned)h) << (16 * e);
            lword |= ((unsigned)lo) << (16 * e);
        }
        hw[d] = hword; lw[d] = lword;
    }
    size_t fb = ((((size_t)k2 * 8 + nt) * 4 + kt) * 2) * 64 + lane;
    wpk[fb]      = u32x4{hw[0], hw[1], hw[2], hw[3]};
    wpk[fb + 64] = u32x4{lw[0], lw[1], lw[2], lw[3]};
}

// ---- main: 256 blocks x 512 thr (8 waves). Block = 64 batches, wave = one 16-r N-tile.
// Chain state v in LDS as TWO bf16 planes (hi, lo), RNE-split once per step at write.
// A-frags are direct ds_read_b128 from the planes -> hi and lo share the load path.
__global__ __launch_bounds__(512, 2) void mps_mfma(
    const float* __restrict__ x, const float* __restrict__ wf,
    const float* __restrict__ wl, const u32x4* __restrict__ wpk,
    float* __restrict__ out)
{
    __shared__ unsigned short vh[2][64 * 128];   // 32 KB  hi plane, [row][l]
    __shared__ unsigned short vl_[2][64 * 128];  // 32 KB  lo plane
    const int tid = threadIdx.x;
    const int lane = tid & 63;
    const int nt = tid >> 6;              // wave id = N-tile (16 r)
    const int bbase = blockIdx.x * 64;
    const int arow = lane & 15;
    const int ag = lane >> 4;

    // init v0: only l<2 nonzero: v[b][r] = wf[0*2+r]*x0 + wf[1*2+r]*x1
    const float wf00 = wf[0], wf01 = wf[1], wf10 = wf[2], wf11 = wf[3];
    for (int idx = tid; idx < 64 * 128; idx += 512) {
        int row = idx >> 7, l = idx & 127;
        float val = 0.f;
        if (l < 2) {
            float x0 = x[(size_t)(bbase + row) * 128 + 0];
            float x1 = x[(size_t)(bbase + row) * 128 + 1];
            val = (l == 0) ? (wf00 * x0 + wf10 * x1) : (wf01 * x0 + wf11 * x1);
        }
        unsigned short h = f32_to_bf16_rne(val);
        float rem = val - bf16_to_f32(h);
        unsigned short lo = f32_to_bf16_rne(rem);
        int byte = (row * 256 + l * 2) ^ ((row & 7) << 4);
        *reinterpret_cast<unsigned short*>(reinterpret_cast<char*>(&vh[0][0]) + byte) = h;
        *reinterpret_cast<unsigned short*>(reinterpret_cast<char*>(&vl_[0][0]) + byte) = lo;
    }
    __syncthreads();

    int cur = 0;
    for (int k = 0; k < NMID; ++k) {
        // x for epilogue (site k+1): per lane, 16 batches' (x0,x1)
        float2 xv[4][4];
        #pragma unroll
        for (int mt = 0; mt < 4; ++mt)
            #pragma unroll
            for (int q = 0; q < 4; ++q)
                xv[mt][q] = *reinterpret_cast<const float2*>(
                    &x[(size_t)(bbase + mt * 16 + ag * 4 + q) * 128 + 2 + 2 * k]);

        f32x4 acc[4][2];
        #pragma unroll
        for (int mt = 0; mt < 4; ++mt) {
            acc[mt][0] = f32x4{0.f, 0.f, 0.f, 0.f};
            acc[mt][1] = f32x4{0.f, 0.f, 0.f, 0.f};
        }

        #pragma unroll
        for (int kt = 0; kt < 4; ++kt) {
            size_t fb0 = ((((size_t)(k * 2 + 0) * 8 + nt) * 4 + kt) * 2) * 64 + lane;
            size_t fb1 = ((((size_t)(k * 2 + 1) * 8 + nt) * 4 + kt) * 2) * 64 + lane;
            short8 bh0 = __builtin_bit_cast(short8, wpk[fb0]);
            short8 bl0 = __builtin_bit_cast(short8, wpk[fb0 + 64]);
            short8 bh1 = __builtin_bit_cast(short8, wpk[fb1]);
            short8 bl1 = __builtin_bit_cast(short8, wpk[fb1 + 64]);

            #pragma unroll
            for (int mt = 0; mt < 4; ++mt) {
                int row = mt * 16 + arow;
                int boff = (row * 256 + kt * 64 + ag * 16) ^ ((row & 7) << 4);
                short8 ah = *reinterpret_cast<short8*>(
                    reinterpret_cast<char*>(&vh[cur][0]) + boff);
                short8 al = *reinterpret_cast<short8*>(
                    reinterpret_cast<char*>(&vl_[cur][0]) + boff);
                // interleave acc0/acc1 to break acc dependence chains
                acc[mt][0] = __builtin_amdgcn_mfma_f32_16x16x32_bf16(ah, bh0, acc[mt][0], 0, 0, 0);
                acc[mt][1] = __builtin_amdgcn_mfma_f32_16x16x32_bf16(ah, bh1, acc[mt][1], 0, 0, 0);
                acc[mt][0] = __builtin_amdgcn_mfma_f32_16x16x32_bf16(al, bh0, acc[mt][0], 0, 0, 0);
                acc[mt][1] = __builtin_amdgcn_mfma_f32_16x16x32_bf16(al, bh1, acc[mt][1], 0, 0, 0);
                acc[mt][0] = __builtin_amdgcn_mfma_f32_16x16x32_bf16(ah, bl0, acc[mt][0], 0, 0, 0);
                acc[mt][1] = __builtin_amdgcn_mfma_f32_16x16x32_bf16(ah, bl1, acc[mt][1], 0, 0, 0);
            }
        }

        // epilogue: vn = x0*acc0 + x1*acc1 (fp32), RNE-split to bf16 hi/lo, store
        const int nxt = cur ^ 1;
        #pragma unroll
        for (int mt = 0; mt < 4; ++mt) {
            #pragma unroll
            for (int q = 0; q < 4; ++q) {
                float vn = xv[mt][q].x * acc[mt][0][q] + xv[mt][q].y * acc[mt][1][q];
                unsigned short h = f32_to_bf16_rne(vn);
                float rem = vn - bf16_to_f32(h);
                unsigned short lo = f32_to_bf16_rne(rem);
                int row = mt * 16 + ag * 4 + q;      // D row = (lane>>4)*4+q
                int col = nt * 16 + arow;            // D col = lane&15
                int byte = (row * 256 + col * 2) ^ ((row & 7) << 4);
                *reinterpret_cast<unsigned short*>(
                    reinterpret_cast<char*>(&vh[nxt][0]) + byte) = h;
                *reinterpret_cast<unsigned short*>(
                    reinterpret_cast<char*>(&vl_[nxt][0]) + byte) = lo;
            }
        }
        cur = nxt;
        __syncthreads();
    }

    // finale: out[b] = v[b,0]*(wl00*x0+wl01*x1) + v[b,1]*(wl10*x0+wl11*x1)
    if (tid < 64) {
        int row = tid;
        int boff = (row * 256) ^ ((row & 7) << 4);
        unsigned hw = *reinterpret_cast<unsigned*>(
            reinterpret_cast<char*>(&vh[cur][0]) + boff);
        unsigned lw = *reinterpret_cast<unsigned*>(
            reinterpret_cast<char*>(&vl_[cur][0]) + boff);
        float v0 = bf16_to_f32((unsigned short)(hw & 0xffffu))
                 + bf16_to_f32((unsigned short)(lw & 0xffffu));
        float v1 = bf16_to_f32((unsigned short)(hw >> 16))
                 + bf16_to_f32((unsigned short)(lw >> 16));
        float x0 = x[(size_t)(bbase + row) * 128 + 126];
        float x1 = x[(size_t)(bbase + row) * 128 + 127];
        out[bbase + row] = v0 * (wl[0] * x0 + wl[1] * x1)
                         + v1 * (wl[2] * x0 + wl[3] * x1);
    }
}

// ---------------- fallback fp32 vector kernel (used only if ws too small) ----
#define BT 32
__global__ __launch_bounds__(256, 2) void mps_chain_kernel(
    const float* __restrict__ x, const float* __restrict__ wf,
    const float* __restrict__ wm, const float* __restrict__ wl,
    float* __restrict__ out)
{
    __shared__ float vbuf[2][128][BT];
    __shared__ float xs_lds[BT][126];
    const int tid = threadIdx.x;
    const int rg = tid >> 3, bg = tid & 7;
    const int r0 = rg * 4, b0 = bg * 4;
    const int bbase = blockIdx.x * BT;
    for (int idx = tid; idx < BT * 126; idx += 256) {
        int b = idx / 126, j = idx % 126;
        xs_lds[b][j] = x[(size_t)(bbase + b) * 128 + 2 + j];
    }
    const float wf00 = wf[0], wf01 = wf[1], wf10 = wf[2], wf11 = wf[3];
    for (int idx = tid; idx < 128 * BT; idx += 256) {
        int l = idx / BT, b = idx % BT;
        float val = 0.0f;
        if (l < 2) {
            float x0 = x[(size_t)(bbase + b) * 128 + 0];
            float x1 = x[(size_t)(bbase + b) * 128 + 1];
            val = (l == 0) ? (wf00 * x0 + wf10 * x1) : (wf01 * x0 + wf11 * x1);
        }
        vbuf[0][l][b] = val;
    }
    __syncthreads();
    int cur = 0;
    for (int k = 0; k < NMID; ++k) {
        const float* __restrict__ Wk = wm + (size_t)k * (2 * 128 * 128);
        float acc0[4][4], acc1[4][4];
        #pragma unroll
        for (int bb = 0; bb < 4; ++bb)
            #pragma unroll
            for (int rr = 0; rr < 4; ++rr) { acc0[bb][rr] = 0.0f; acc1[bb][rr] = 0.0f; }
        #pragma unroll 4
        for (int l = 0; l < 128; ++l) {
            float4 vv = *reinterpret_cast<const float4*>(&vbuf[cur][l][b0]);
            float4 w0 = *reinterpret_cast<const float4*>(&Wk[(size_t)(2 * l) * 128 + r0]);
            float4 w1 = *reinterpret_cast<const float4*>(&Wk[(size_t)(2 * l + 1) * 128 + r0]);
            float va[4] = { vv.x, vv.y, vv.z, vv.w };
            float w0a[4] = { w0.x, w0.y, w0.z, w0.w };
            float w1a[4] = { w1.x, w1.y, w1.z, w1.w };
            #pragma unroll
            for (int bb = 0; bb < 4; ++bb)
                #pragma unroll
                for (int rr = 0; rr < 4; ++rr) {
                    acc0[bb][rr] = fmaf(va[bb], w0a[rr], acc0[bb][rr]);
                    acc1[bb][rr] = fmaf(va[bb], w1a[rr], acc1[bb][rr]);
                }
        }
        const int nxt = cur ^ 1;
        float vn[4][4];
        #pragma unroll
        for (int bb = 0; bb < 4; ++bb) {
            float xx0 = xs_lds[b0 + bb][2 * k + 0];
            float xx1 = xs_lds[b0 + bb][2 * k + 1];
            #pragma unroll
            for (int rr = 0; rr < 4; ++rr)
                vn[bb][rr] = xx0 * acc0[bb][rr] + xx1 * acc1[bb][rr];
        }
        #pragma unroll
        for (int rr = 0; rr < 4; ++rr) {
            float4 wv = make_float4(vn[0][rr], vn[1][rr], vn[2][rr], vn[3][rr]);
            *reinterpret_cast<float4*>(&vbuf[nxt][r0 + rr][b0]) = wv;
        }
        cur = nxt;
        __syncthreads();
    }
    if (rg == 0) {
        const float wl00 = wl[0], wl01 = wl[1], wl10 = wl[2], wl11 = wl[3];
        #pragma unroll
        for (int bb = 0; bb < 4; ++bb) {
            int b = b0 + bb;
            float v0 = vbuf[cur][0][b];
            float v1 = vbuf[cur][1][b];
            float xx0 = xs_lds[b][124];
            float xx1 = xs_lds[b][125];
            out[bbase + b] = v0 * (wl00 * xx0 + wl01 * xx1)
                           + v1 * (wl10 * xx0 + wl11 * xx1);
        }
    }
}

extern "C" void kernel_launch(void* const* d_in, const int* in_sizes, int n_in,
                              void* d_out, int out_size, void* d_ws, size_t ws_size,
                              hipStream_t stream) {
    const float* x  = (const float*)d_in[0];
    const float* wf = (const float*)d_in[1];
    const float* wm = (const float*)d_in[2];
    const float* wl = (const float*)d_in[3];
    float* out = (float*)d_out;

    const size_t ws_needed = (size_t)124 * 8 * 4 * 2 * 64 * 16;  // 8.1 MB packed W
    if (ws_size >= ws_needed) {
        u32x4* wpk = (u32x4*)d_ws;
        hipLaunchKernelGGL(mps_pack_w, dim3(992), dim3(256), 0, stream, wm, wpk);
        hipLaunchKernelGGL(mps_mfma, dim3(NBATCH / 64), dim3(512), 0, stream,
                           x, wf, wl, wpk, out);
    } else {
        hipLaunchKernelGGL(mps_chain_kernel, dim3(NBATCH / BT), dim3(256), 0, stream,
                           x, wf, wm, wl, out);
    }
}

// Round 6
// 164.275 us; speedup vs baseline: 5.6233x; 1.6924x over previous
//
#include <hip/hip_runtime.h>
#include <stdint.h>

#define NMID 62
#define NBATCH 16384

typedef __attribute__((ext_vector_type(8))) _Float16 half8;
typedef __attribute__((ext_vector_type(4))) float f32x4;
typedef __attribute__((ext_vector_type(4))) unsigned int u32x4;

__device__ __forceinline__ unsigned short f16_bits(float f) {
    _Float16 h = (_Float16)f;              // v_cvt_f16_f32, RNE (default mode)
    return __builtin_bit_cast(unsigned short, h);
}

// Bond-dimension schedule r_k (output bond of middle site k), k = 0..61:
// 4,8,16,32,64,128,...(128)...,64,32,16,8,4,2
__device__ __forceinline__ float g_scale(int k) {
    int rk = (k < 5) ? (4 << k) : ((k < 56) ? 128 : (64 >> (k - 56)));
    return 16.0f * rsqrtf((float)rk);
}

// ---- prep: pack W[62,128,2,128] fp32 -> f16 MFMA B-fragment order ----
// frag addr (u32x4 units): f = (((k*2+i)*8 + nt)*4 + kt)*64 + lane.
// B-frag (16x16x32): lane holds B[kdim=(lane>>4)*8+j][col=lane&15], j=0..7, 2 f16/dword.
// Contraction dim = l (global l = kt*32 + (lane>>4)*8 + j), col r = nt*16+(lane&15).
__global__ void mps_pack_w(const float* __restrict__ wm, u32x4* __restrict__ wpk) {
    int t = blockIdx.x * blockDim.x + threadIdx.x;
    if (t >= 124 * 8 * 4 * 64) return;
    int lane = t & 63;
    int kt = (t >> 6) & 3;
    int nt = (t >> 8) & 7;
    int k2 = t >> 11;                 // k*2 + i
    int k = k2 >> 1, i = k2 & 1;
    int r = nt * 16 + (lane & 15);
    int lbase = kt * 32 + (lane >> 4) * 8;
    unsigned wd[4];
    #pragma unroll
    for (int d = 0; d < 4; ++d) {
        unsigned lo = f16_bits(wm[((size_t)k * 128 + (lbase + d * 2 + 0)) * 256 + i * 128 + r]);
        unsigned hi = f16_bits(wm[((size_t)k * 128 + (lbase + d * 2 + 1)) * 256 + i * 128 + r]);
        wd[d] = lo | (hi << 16);
    }
    wpk[(((size_t)k2 * 8 + nt) * 4 + kt) * 64 + lane] = u32x4{wd[0], wd[1], wd[2], wd[3]};
}

// One chain step with input-normalized static scaling:
//   v_new = s * (x0*acc0 + x1*acc1),  s = G_k * rsqrt(x0^2+x1^2)
// keeps ||v_stored|| ~ const so f16 never under/overflows. No cross-thread
// bookkeeping: the finale recomputes the identical product of s factors from x.
__device__ __forceinline__ void do_step(
    int k, const float* __restrict__ x, int bbase, int lane, int nt,
    const unsigned short* __restrict__ vcur, unsigned short* __restrict__ vnxt,
    const u32x4* __restrict__ wpk)
{
    const int arow = lane & 15, ag = lane >> 4;
    const float Gk = g_scale(k);

    // B fragments for this step (8 x dwordx4 from L2-resident packed W)
    u32x4 bf[8];   // [i*4 + kt]
    #pragma unroll
    for (int i = 0; i < 2; ++i)
        #pragma unroll
        for (int kt = 0; kt < 4; ++kt)
            bf[i * 4 + kt] = wpk[(((size_t)(k * 2 + i) * 8 + nt) * 4 + kt) * 64 + lane];

    // epilogue x values — issue early, consumed after MFMA phase
    float2 xv[4][4];
    #pragma unroll
    for (int mt = 0; mt < 4; ++mt)
        #pragma unroll
        for (int q = 0; q < 4; ++q)
            xv[mt][q] = *reinterpret_cast<const float2*>(
                &x[(size_t)(bbase + mt * 16 + ag * 4 + q) * 128 + 2 + 2 * k]);

    f32x4 acc[4][2];
    #pragma unroll
    for (int mt = 0; mt < 4; ++mt) {
        acc[mt][0] = f32x4{0.f, 0.f, 0.f, 0.f};
        acc[mt][1] = f32x4{0.f, 0.f, 0.f, 0.f};
    }

    #pragma unroll
    for (int kt = 0; kt < 4; ++kt) {
        half8 a[4];
        #pragma unroll
        for (int mt = 0; mt < 4; ++mt) {
            int row = mt * 16 + arow;
            int boff = (row * 256 + kt * 64 + ag * 16) ^ ((row & 7) << 4);
            a[mt] = *reinterpret_cast<const half8*>(
                reinterpret_cast<const char*>(vcur) + boff);
        }
        #pragma unroll
        for (int mt = 0; mt < 4; ++mt) {
            acc[mt][0] = __builtin_amdgcn_mfma_f32_16x16x32_f16(
                a[mt], __builtin_bit_cast(half8, bf[kt]), acc[mt][0], 0, 0, 0);
            acc[mt][1] = __builtin_amdgcn_mfma_f32_16x16x32_f16(
                a[mt], __builtin_bit_cast(half8, bf[4 + kt]), acc[mt][1], 0, 0, 0);
        }
    }

    // epilogue: vn = s*(x0*acc0 + x1*acc1) (fp32), RNE f16, store swizzled
    #pragma unroll
    for (int mt = 0; mt < 4; ++mt)
        #pragma unroll
        for (int q = 0; q < 4; ++q) {
            float x0 = xv[mt][q].x, x1 = xv[mt][q].y;
            float n2 = fmaf(x0, x0, fmaf(x1, x1, 1e-30f));
            float s = Gk * rsqrtf(n2);
            float vn = s * fmaf(x0, acc[mt][0][q], x1 * acc[mt][1][q]);
            int row = mt * 16 + ag * 4 + q;      // D row = (lane>>4)*4+q
            int col = nt * 16 + arow;            // D col = lane&15
            int byte = (row * 256 + col * 2) ^ ((row & 7) << 4);
            *reinterpret_cast<unsigned short*>(
                reinterpret_cast<char*>(vnxt) + byte) = f16_bits(vn);
        }
    __syncthreads();
}

// ---- main: 256 blocks x 512 thr (8 waves = 8 N-tiles). Block = 64 batches. ----
__global__ __launch_bounds__(512, 2) void mps_mfma(
    const float* __restrict__ x, const float* __restrict__ wf,
    const float* __restrict__ wl, const u32x4* __restrict__ wpk,
    float* __restrict__ out)
{
    __shared__ unsigned short vh[2][64 * 128];   // 16 KB each, ping-pong
    const int tid = threadIdx.x;
    const int lane = tid & 63;
    const int nt = tid >> 6;
    const int bbase = blockIdx.x * 64;

    // init v0 (only l<2 nonzero), normalized by s_init = 8*rsqrt(x0^2+x1^2) so the
    // stored f16 state is mid-range for every batch.
    const float wf00 = wf[0], wf01 = wf[1], wf10 = wf[2], wf11 = wf[3];
    for (int idx = tid; idx < 64 * 128; idx += 512) {
        int row = idx >> 7, l = idx & 127;
        float val = 0.f;
        if (l < 2) {
            float x0 = x[(size_t)(bbase + row) * 128 + 0];
            float x1 = x[(size_t)(bbase + row) * 128 + 1];
            float n2 = fmaf(x0, x0, fmaf(x1, x1, 1e-30f));
            float si = 8.0f * rsqrtf(n2);
            val = si * ((l == 0) ? (wf00 * x0 + wf10 * x1) : (wf01 * x0 + wf11 * x1));
        }
        int byte = (row * 256 + l * 2) ^ ((row & 7) << 4);
        *reinterpret_cast<unsigned short*>(
            reinterpret_cast<char*>(&vh[0][0]) + byte) = f16_bits(val);
    }
    __syncthreads();

    // plain ping-pong loop, unrolled by 2 for static buffer naming; B-frags are
    // loaded inside each step (no cross-step prefetch, no loop-carried state).
    for (int kk = 0; kk < NMID; kk += 2) {
        do_step(kk,     x, bbase, lane, nt, &vh[0][0], &vh[1][0], wpk);
        do_step(kk + 1, x, bbase, lane, nt, &vh[1][0], &vh[0][0], wpk);
    }

    // finale: recompute the scale product alpha from x (identical rsqrtf factors
    // as applied in the chain -> no cross-thread communication needed), then
    // out[b] = (v0*(wl00*x0+wl01*x1) + v1*(wl10*x0+wl11*x1)) / alpha
    if (tid < 64) {
        int row = tid;
        const float* xb = &x[(size_t)(bbase + row) * 128];
        float n2i = fmaf(xb[0], xb[0], fmaf(xb[1], xb[1], 1e-30f));
        float alpha = 8.0f * rsqrtf(n2i);
        for (int k = 0; k < NMID; ++k) {
            float2 xx = *reinterpret_cast<const float2*>(&xb[2 + 2 * k]);
            float n2 = fmaf(xx.x, xx.x, fmaf(xx.y, xx.y, 1e-30f));
            alpha *= g_scale(k) * rsqrtf(n2);
        }
        int boff = (row * 256) ^ ((row & 7) << 4);
        unsigned hw = *reinterpret_cast<unsigned*>(
            reinterpret_cast<char*>(&vh[0][0]) + boff);
        float v0 = (float)__builtin_bit_cast(_Float16, (unsigned short)(hw & 0xffffu));
        float v1 = (float)__builtin_bit_cast(_Float16, (unsigned short)(hw >> 16));
        float x0 = xb[126], x1 = xb[127];
        float val = v0 * (wl[0] * x0 + wl[1] * x1)
                  + v1 * (wl[2] * x0 + wl[3] * x1);
        out[bbase + row] = val / alpha;
    }
}

// ---------------- fallback fp32 vector kernel (used only if ws too small) ----
#define BT 32
__global__ __launch_bounds__(256, 2) void mps_chain_kernel(
    const float* __restrict__ x, const float* __restrict__ wf,
    const float* __restrict__ wm, const float* __restrict__ wl,
    float* __restrict__ out)
{
    __shared__ float vbuf[2][128][BT];
    __shared__ float xs_lds[BT][126];
    const int tid = threadIdx.x;
    const int rg = tid >> 3, bg = tid & 7;
    const int r0 = rg * 4, b0 = bg * 4;
    const int bbase = blockIdx.x * BT;
    for (int idx = tid; idx < BT * 126; idx += 256) {
        int b = idx / 126, j = idx % 126;
        xs_lds[b][j] = x[(size_t)(bbase + b) * 128 + 2 + j];
    }
    const float wf00 = wf[0], wf01 = wf[1], wf10 = wf[2], wf11 = wf[3];
    for (int idx = tid; idx < 128 * BT; idx += 256) {
        int l = idx / BT, b = idx % BT;
        float val = 0.0f;
        if (l < 2) {
            float x0 = x[(size_t)(bbase + b) * 128 + 0];
            float x1 = x[(size_t)(bbase + b) * 128 + 1];
            val = (l == 0) ? (wf00 * x0 + wf10 * x1) : (wf01 * x0 + wf11 * x1);
        }
        vbuf[0][l][b] = val;
    }
    __syncthreads();
    int cur = 0;
    for (int k = 0; k < NMID; ++k) {
        const float* __restrict__ Wk = wm + (size_t)k * (2 * 128 * 128);
        float acc0[4][4], acc1[4][4];
        #pragma unroll
        for (int bb = 0; bb < 4; ++bb)
            #pragma unroll
            for (int rr = 0; rr < 4; ++rr) { acc0[bb][rr] = 0.0f; acc1[bb][rr] = 0.0f; }
        #pragma unroll 4
        for (int l = 0; l < 128; ++l) {
            float4 vv = *reinterpret_cast<const float4*>(&vbuf[cur][l][b0]);
            float4 w0 = *reinterpret_cast<const float4*>(&Wk[(size_t)(2 * l) * 128 + r0]);
            float4 w1 = *reinterpret_cast<const float4*>(&Wk[(size_t)(2 * l + 1) * 128 + r0]);
            float va[4] = { vv.x, vv.y, vv.z, vv.w };
            float w0a[4] = { w0.x, w0.y, w0.z, w0.w };
            float w1a[4] = { w1.x, w1.y, w1.z, w1.w };
            #pragma unroll
            for (int bb = 0; bb < 4; ++bb)
                #pragma unroll
                for (int rr = 0; rr < 4; ++rr) {
                    acc0[bb][rr] = fmaf(va[bb], w0a[rr], acc0[bb][rr]);
                    acc1[bb][rr] = fmaf(va[bb], w1a[rr], acc1[bb][rr]);
                }
        }
        const int nxt = cur ^ 1;
        float vn[4][4];
        #pragma unroll
        for (int bb = 0; bb < 4; ++bb) {
            float xx0 = xs_lds[b0 + bb][2 * k + 0];
            float xx1 = xs_lds[b0 + bb][2 * k + 1];
            #pragma unroll
            for (int rr = 0; rr < 4; ++rr)
                vn[bb][rr] = xx0 * acc0[bb][rr] + xx1 * acc1[bb][rr];
        }
        #pragma unroll
        for (int rr = 0; rr < 4; ++rr) {
            float4 wv = make_float4(vn[0][rr], vn[1][rr], vn[2][rr], vn[3][rr]);
            *reinterpret_cast<float4*>(&vbuf[nxt][r0 + rr][b0]) = wv;
        }
        cur = nxt;
        __syncthreads();
    }
    if (rg == 0) {
        const float wl00 = wl[0], wl01 = wl[1], wl10 = wl[2], wl11 = wl[3];
        #pragma unroll
        for (int bb = 0; bb < 4; ++bb) {
            int b = b0 + bb;
            float v0 = vbuf[cur][0][b];
            float v1 = vbuf[cur][1][b];
            float xx0 = xs_lds[b][124];
            float xx1 = xs_lds[b][125];
            out[bbase + b] = v0 * (wl00 * xx0 + wl01 * xx1)
                           + v1 * (wl10 * xx0 + wl11 * xx1);
        }
    }
}

extern "C" void kernel_launch(void* const* d_in, const int* in_sizes, int n_in,
                              void* d_out, int out_size, void* d_ws, size_t ws_size,
                              hipStream_t stream) {
    const float* x  = (const float*)d_in[0];
    const float* wf = (const float*)d_in[1];
    const float* wm = (const float*)d_in[2];
    const float* wl = (const float*)d_in[3];
    float* out = (float*)d_out;

    const size_t ws_needed = (size_t)124 * 8 * 4 * 64 * 16;  // 4.06 MB packed W (f16)
    if (ws_size >= ws_needed) {
        u32x4* wpk = (u32x4*)d_ws;
        hipLaunchKernelGGL(mps_pack_w, dim3(992), dim3(256), 0, stream, wm, wpk);
        hipLaunchKernelGGL(mps_mfma, dim3(NBATCH / 64), dim3(512), 0, stream,
                           x, wf, wl, wpk, out);
    } else {
        hipLaunchKernelGGL(mps_chain_kernel, dim3(NBATCH / BT), dim3(256), 0, stream,
                           x, wf, wm, wl, out);
    }
}

// Round 7
// 147.773 us; speedup vs baseline: 6.2513x; 1.1117x over previous
//
#include <hip/hip_runtime.h>
#include <stdint.h>

#define NMID 62
#define NBATCH 16384
#define BT 32            // batches per block

typedef __attribute__((ext_vector_type(8))) _Float16 half8;
typedef __attribute__((ext_vector_type(4))) float f32x4;
typedef __attribute__((ext_vector_type(4))) unsigned int u32x4;

__device__ __forceinline__ unsigned short f16_bits(float f) {
    _Float16 h = (_Float16)f;              // v_cvt_f16_f32, RNE (default mode)
    return __builtin_bit_cast(unsigned short, h);
}

// Bond-dimension schedule r_k (output bond of middle site k), k = 0..61:
// 4,8,16,32,64,128,...(128)...,64,32,16,8,4,2
__device__ __forceinline__ float g_scale(int k) {
    int rk = (k < 5) ? (4 << k) : ((k < 56) ? 128 : (64 >> (k - 56)));
    return 16.0f * rsqrtf((float)rk);
}

// ---- prep: pack W[62,128,2,128] fp32 -> f16 MFMA B-fragment order ----
// frag addr (u32x4 units): f = (((k*2+i)*8 + nt)*4 + kt)*64 + lane.
// B-frag (16x16x32): lane holds B[kdim=(lane>>4)*8+j][col=lane&15], j=0..7, 2 f16/dword.
// Contraction dim = l (global l = kt*32 + (lane>>4)*8 + j), col r = nt*16+(lane&15).
__global__ void mps_pack_w(const float* __restrict__ wm, u32x4* __restrict__ wpk) {
    int t = blockIdx.x * blockDim.x + threadIdx.x;
    if (t >= 124 * 8 * 4 * 64) return;
    int lane = t & 63;
    int kt = (t >> 6) & 3;
    int nt = (t >> 8) & 7;
    int k2 = t >> 11;                 // k*2 + i
    int k = k2 >> 1, i = k2 & 1;
    int r = nt * 16 + (lane & 15);
    int lbase = kt * 32 + (lane >> 4) * 8;
    unsigned wd[4];
    #pragma unroll
    for (int d = 0; d < 4; ++d) {
        unsigned lo = f16_bits(wm[((size_t)k * 128 + (lbase + d * 2 + 0)) * 256 + i * 128 + r]);
        unsigned hi = f16_bits(wm[((size_t)k * 128 + (lbase + d * 2 + 1)) * 256 + i * 128 + r]);
        wd[d] = lo | (hi << 16);
    }
    wpk[(((size_t)k2 * 8 + nt) * 4 + kt) * 64 + lane] = u32x4{wd[0], wd[1], wd[2], wd[3]};
}

// One chain step. v stored f16 in LDS [row][l] with XOR swizzle byte ^= (row&7)<<4.
// x-hat (pre-scaled x, f32x2) comes from LDS (broadcast reads).
__device__ __forceinline__ void do_step(
    int k, const float* __restrict__ xh, int lane, int nt,
    const unsigned short* __restrict__ vcur, unsigned short* __restrict__ vnxt,
    const u32x4* __restrict__ wpk)
{
    const int arow = lane & 15, ag = lane >> 4;

    // B fragments for this step (8 x dwordx4 from L2-resident packed W)
    u32x4 bf[8];   // [i*4 + kt]
    #pragma unroll
    for (int i = 0; i < 2; ++i)
        #pragma unroll
        for (int kt = 0; kt < 4; ++kt)
            bf[i * 4 + kt] = wpk[(((size_t)(k * 2 + i) * 8 + nt) * 4 + kt) * 64 + lane];

    // epilogue x-hat values (LDS broadcast) — issue early
    float2 xv[2][4];
    #pragma unroll
    for (int mt = 0; mt < 2; ++mt)
        #pragma unroll
        for (int q = 0; q < 4; ++q)
            xv[mt][q] = *reinterpret_cast<const float2*>(
                &xh[(k * BT + mt * 16 + ag * 4 + q) * 2]);

    f32x4 acc[2][2];
    #pragma unroll
    for (int mt = 0; mt < 2; ++mt) {
        acc[mt][0] = f32x4{0.f, 0.f, 0.f, 0.f};
        acc[mt][1] = f32x4{0.f, 0.f, 0.f, 0.f};
    }

    #pragma unroll
    for (int kt = 0; kt < 4; ++kt) {
        half8 a[2];
        #pragma unroll
        for (int mt = 0; mt < 2; ++mt) {
            int row = mt * 16 + arow;
            int boff = (row * 256 + kt * 64 + ag * 16) ^ ((row & 7) << 4);
            a[mt] = *reinterpret_cast<const half8*>(
                reinterpret_cast<const char*>(vcur) + boff);
        }
        #pragma unroll
        for (int mt = 0; mt < 2; ++mt) {
            acc[mt][0] = __builtin_amdgcn_mfma_f32_16x16x32_f16(
                a[mt], __builtin_bit_cast(half8, bf[kt]), acc[mt][0], 0, 0, 0);
            acc[mt][1] = __builtin_amdgcn_mfma_f32_16x16x32_f16(
                a[mt], __builtin_bit_cast(half8, bf[4 + kt]), acc[mt][1], 0, 0, 0);
        }
    }

    // epilogue: vn = xh0*acc0 + xh1*acc1 (s already folded into xh), f16 store
    #pragma unroll
    for (int mt = 0; mt < 2; ++mt)
        #pragma unroll
        for (int q = 0; q < 4; ++q) {
            float vn = fmaf(xv[mt][q].x, acc[mt][0][q], xv[mt][q].y * acc[mt][1][q]);
            int row = mt * 16 + ag * 4 + q;      // D row = (lane>>4)*4+q
            int col = nt * 16 + arow;            // D col = lane&15
            int byte = (row * 256 + col * 2) ^ ((row & 7) << 4);
            *reinterpret_cast<unsigned short*>(
                reinterpret_cast<char*>(vnxt) + byte) = f16_bits(vn);
        }
    __syncthreads();
}

// ---- main: 512 blocks x 512 thr (8 waves = 8 N-tiles). Block = 32 batches.
// 2 blocks/CU -> two independent barrier domains overlap MFMA vs epilogue phases.
__global__ __launch_bounds__(512, 4) void mps_mfma(
    const float* __restrict__ x, const float* __restrict__ wf,
    const float* __restrict__ wl, const u32x4* __restrict__ wpk,
    float* __restrict__ out)
{
    __shared__ unsigned short vh[2][BT * 128];   // 8 KB each, ping-pong
    __shared__ float xh[NMID * BT * 2];          // 15.5 KB pre-scaled x
    const int tid = threadIdx.x;
    const int lane = tid & 63;
    const int nt = tid >> 6;
    const int bbase = blockIdx.x * BT;

    // prologue A: x-hat[k][row] = s * x(site k+1),  s = G_k * rsqrt(x0^2+x1^2)
    for (int idx = tid; idx < NMID * BT; idx += 512) {
        int k = idx >> 5, row = idx & 31;
        float2 xx = *reinterpret_cast<const float2*>(
            &x[(size_t)(bbase + row) * 128 + 2 + 2 * k]);
        float n2 = fmaf(xx.x, xx.x, fmaf(xx.y, xx.y, 1e-30f));
        float s = g_scale(k) * rsqrtf(n2);
        xh[idx * 2 + 0] = s * xx.x;
        xh[idx * 2 + 1] = s * xx.y;
    }

    // prologue B: v0 (only l<2 nonzero), normalized by s_init = 8*rsqrt(x0^2+x1^2)
    const float wf00 = wf[0], wf01 = wf[1], wf10 = wf[2], wf11 = wf[3];
    for (int idx = tid; idx < BT * 128; idx += 512) {
        int row = idx >> 7, l = idx & 127;
        float val = 0.f;
        if (l < 2) {
            float x0 = x[(size_t)(bbase + row) * 128 + 0];
            float x1 = x[(size_t)(bbase + row) * 128 + 1];
            float n2 = fmaf(x0, x0, fmaf(x1, x1, 1e-30f));
            float si = 8.0f * rsqrtf(n2);
            val = si * ((l == 0) ? (wf00 * x0 + wf10 * x1) : (wf01 * x0 + wf11 * x1));
        }
        int byte = (row * 256 + l * 2) ^ ((row & 7) << 4);
        *reinterpret_cast<unsigned short*>(
            reinterpret_cast<char*>(&vh[0][0]) + byte) = f16_bits(val);
    }
    __syncthreads();

    // ping-pong chain loop, unrolled by 2 for static buffer naming
    for (int kk = 0; kk < NMID; kk += 2) {
        do_step(kk,     xh, lane, nt, &vh[0][0], &vh[1][0], wpk);
        do_step(kk + 1, xh, lane, nt, &vh[1][0], &vh[0][0], wpk);
    }

    // finale: recompute alpha = s_init * prod_k s_k from GLOBAL x (bitwise the
    // same rsqrtf factors as the prologue; no cross-thread communication), then
    // out[b] = (v0*(wl00*x0+wl01*x1) + v1*(wl10*x0+wl11*x1)) / alpha
    if (tid < BT) {
        int row = tid;
        const float* xb = &x[(size_t)(bbase + row) * 128];
        float n2i = fmaf(xb[0], xb[0], fmaf(xb[1], xb[1], 1e-30f));
        float alpha = 8.0f * rsqrtf(n2i);
        for (int k = 0; k < NMID; ++k) {
            float2 xx = *reinterpret_cast<const float2*>(&xb[2 + 2 * k]);
            float n2 = fmaf(xx.x, xx.x, fmaf(xx.y, xx.y, 1e-30f));
            alpha *= g_scale(k) * rsqrtf(n2);
        }
        int boff = (row * 256) ^ ((row & 7) << 4);
        unsigned hw = *reinterpret_cast<unsigned*>(
            reinterpret_cast<char*>(&vh[0][0]) + boff);
        float v0 = (float)__builtin_bit_cast(_Float16, (unsigned short)(hw & 0xffffu));
        float v1 = (float)__builtin_bit_cast(_Float16, (unsigned short)(hw >> 16));
        float x0 = xb[126], x1 = xb[127];
        float val = v0 * (wl[0] * x0 + wl[1] * x1)
                  + v1 * (wl[2] * x0 + wl[3] * x1);
        out[bbase + row] = val / alpha;
    }
}

// ---------------- fallback fp32 vector kernel (used only if ws too small) ----
#define FBT 32
__global__ __launch_bounds__(256, 2) void mps_chain_kernel(
    const float* __restrict__ x, const float* __restrict__ wf,
    const float* __restrict__ wm, const float* __restrict__ wl,
    float* __restrict__ out)
{
    __shared__ float vbuf[2][128][FBT];
    __shared__ float xs_lds[FBT][126];
    const int tid = threadIdx.x;
    const int rg = tid >> 3, bg = tid & 7;
    const int r0 = rg * 4, b0 = bg * 4;
    const int bbase = blockIdx.x * FBT;
    for (int idx = tid; idx < FBT * 126; idx += 256) {
        int b = idx / 126, j = idx % 126;
        xs_lds[b][j] = x[(size_t)(bbase + b) * 128 + 2 + j];
    }
    const float wf00 = wf[0], wf01 = wf[1], wf10 = wf[2], wf11 = wf[3];
    for (int idx = tid; idx < 128 * FBT; idx += 256) {
        int l = idx / FBT, b = idx % FBT;
        float val = 0.0f;
        if (l < 2) {
            float x0 = x[(size_t)(bbase + b) * 128 + 0];
            float x1 = x[(size_t)(bbase + b) * 128 + 1];
            val = (l == 0) ? (wf00 * x0 + wf10 * x1) : (wf01 * x0 + wf11 * x1);
        }
        vbuf[0][l][b] = val;
    }
    __syncthreads();
    int cur = 0;
    for (int k = 0; k < NMID; ++k) {
        const float* __restrict__ Wk = wm + (size_t)k * (2 * 128 * 128);
        float acc0[4][4], acc1[4][4];
        #pragma unroll
        for (int bb = 0; bb < 4; ++bb)
            #pragma unroll
            for (int rr = 0; rr < 4; ++rr) { acc0[bb][rr] = 0.0f; acc1[bb][rr] = 0.0f; }
        #pragma unroll 4
        for (int l = 0; l < 128; ++l) {
            float4 vv = *reinterpret_cast<const float4*>(&vbuf[cur][l][b0]);
            float4 w0 = *reinterpret_cast<const float4*>(&Wk[(size_t)(2 * l) * 128 + r0]);
            float4 w1 = *reinterpret_cast<const float4*>(&Wk[(size_t)(2 * l + 1) * 128 + r0]);
            float va[4] = { vv.x, vv.y, vv.z, vv.w };
            float w0a[4] = { w0.x, w0.y, w0.z, w0.w };
            float w1a[4] = { w1.x, w1.y, w1.z, w1.w };
            #pragma unroll
            for (int bb = 0; bb < 4; ++bb)
                #pragma unroll
                for (int rr = 0; rr < 4; ++rr) {
                    acc0[bb][rr] = fmaf(va[bb], w0a[rr], acc0[bb][rr]);
                    acc1[bb][rr] = fmaf(va[bb], w1a[rr], acc1[bb][rr]);
                }
        }
        const int nxt = cur ^ 1;
        float vn[4][4];
        #pragma unroll
        for (int bb = 0; bb < 4; ++bb) {
            float xx0 = xs_lds[b0 + bb][2 * k + 0];
            float xx1 = xs_lds[b0 + bb][2 * k + 1];
            #pragma unroll
            for (int rr = 0; rr < 4; ++rr)
                vn[bb][rr] = xx0 * acc0[bb][rr] + xx1 * acc1[bb][rr];
        }
        #pragma unroll
        for (int rr = 0; rr < 4; ++rr) {
            float4 wv = make_float4(vn[0][rr], vn[1][rr], vn[2][rr], vn[3][rr]);
            *reinterpret_cast<float4*>(&vbuf[nxt][r0 + rr][b0]) = wv;
        }
        cur = nxt;
        __syncthreads();
    }
    if (rg == 0) {
        const float wl00 = wl[0], wl01 = wl[1], wl10 = wl[2], wl11 = wl[3];
        #pragma unroll
        for (int bb = 0; bb < 4; ++bb) {
            int b = b0 + bb;
            float v0 = vbuf[cur][0][b];
            float v1 = vbuf[cur][1][b];
            float xx0 = xs_lds[b][124];
            float xx1 = xs_lds[b][125];
            out[bbase + b] = v0 * (wl00 * xx0 + wl01 * xx1)
                           + v1 * (wl10 * xx0 + wl11 * xx1);
        }
    }
}

extern "C" void kernel_launch(void* const* d_in, const int* in_sizes, int n_in,
                              void* d_out, int out_size, void* d_ws, size_t ws_size,
                              hipStream_t stream) {
    const float* x  = (const float*)d_in[0];
    const float* wf = (const float*)d_in[1];
    const float* wm = (const float*)d_in[2];
    const float* wl = (const float*)d_in[3];
    float* out = (float*)d_out;

    const size_t ws_needed = (size_t)124 * 8 * 4 * 64 * 16;  // 4.06 MB packed W (f16)
    if (ws_size >= ws_needed) {
        u32x4* wpk = (u32x4*)d_ws;
        hipLaunchKernelGGL(mps_pack_w, dim3(992), dim3(256), 0, stream, wm, wpk);
        hipLaunchKernelGGL(mps_mfma, dim3(NBATCH / BT), dim3(512), 0, stream,
                           x, wf, wl, wpk, out);
    } else {
        hipLaunchKernelGGL(mps_chain_kernel, dim3(NBATCH / FBT), dim3(256), 0, stream,
                           x, wf, wm, wl, out);
    }
}

// Round 8
// 102.933 us; speedup vs baseline: 8.9745x; 1.4356x over previous
//
#include <hip/hip_runtime.h>
#include <stdint.h>

#define NMID 62
#define NBATCH 16384
#define BT 32            // batches per block

typedef __attribute__((ext_vector_type(8))) _Float16 half8;
typedef __attribute__((ext_vector_type(4))) float f32x4;
typedef __attribute__((ext_vector_type(4))) unsigned int u32x4;

__device__ __forceinline__ unsigned short f16_bits(float f) {
    _Float16 h = (_Float16)f;              // v_cvt_f16_f32, RNE (default mode)
    return __builtin_bit_cast(unsigned short, h);
}

// Bond-dimension schedule r_k (output bond of middle site k), k = 0..61:
// 4,8,16,32,64,128,...(128)...,64,32,16,8,4,2
__device__ __forceinline__ float g_scale(int k) {
    int rk = (k < 5) ? (4 << k) : ((k < 56) ? 128 : (64 >> (k - 56)));
    return 16.0f * rsqrtf((float)rk);
}

// ---- prep: pack W[62,128,2,128] fp32 -> f16 MFMA B-fragment order ----
// frag addr (u32x4 units): f = (((k*2+i)*8 + nt)*4 + kt)*64 + lane.
// B-frag (16x16x32): lane holds B[kdim=(lane>>4)*8+j][col=lane&15], j=0..7, 2 f16/dword.
// Contraction dim = l (global l = kt*32 + (lane>>4)*8 + j), col r = nt*16+(lane&15).
__global__ void mps_pack_w(const float* __restrict__ wm, u32x4* __restrict__ wpk) {
    int t = blockIdx.x * blockDim.x + threadIdx.x;
    if (t >= 124 * 8 * 4 * 64) return;
    int lane = t & 63;
    int kt = (t >> 6) & 3;
    int nt = (t >> 8) & 7;
    int k2 = t >> 11;                 // k*2 + i
    int k = k2 >> 1, i = k2 & 1;
    int r = nt * 16 + (lane & 15);
    int lbase = kt * 32 + (lane >> 4) * 8;
    unsigned wd[4];
    #pragma unroll
    for (int d = 0; d < 4; ++d) {
        unsigned lo = f16_bits(wm[((size_t)k * 128 + (lbase + d * 2 + 0)) * 256 + i * 128 + r]);
        unsigned hi = f16_bits(wm[((size_t)k * 128 + (lbase + d * 2 + 1)) * 256 + i * 128 + r]);
        wd[d] = lo | (hi << 16);
    }
    wpk[(((size_t)k2 * 8 + nt) * 4 + kt) * 64 + lane] = u32x4{wd[0], wd[1], wd[2], wd[3]};
}

__device__ __forceinline__ void load_b(const u32x4* __restrict__ wpk, int k, int nt,
                                       int lane, u32x4 (&B)[8]) {
    #pragma unroll
    for (int i = 0; i < 2; ++i)
        #pragma unroll
        for (int kt = 0; kt < 4; ++kt)
            B[i * 4 + kt] = wpk[(((size_t)(k * 2 + i) * 8 + nt) * 4 + kt) * 64 + lane];
}

// One chain step. v stored f16 in LDS [row][l] with XOR swizzle byte ^= (row&7)<<4.
// x-hat (pre-scaled x, f32x2) comes from LDS (broadcast reads).
// Bcur: this step's B fragments (already in registers). At the TOP we issue the
// loads for Bnxt (step knext); after the MFMA cluster we pin Bnxt with an asm
// liveness touch — forcing issue-before-MFMA and completion-under-MFMA, so the
// L2 latency is off the critical path of step knext.
__device__ __forceinline__ void do_step(
    int k, const float* __restrict__ xh, int lane, int nt,
    const unsigned short* __restrict__ vcur, unsigned short* __restrict__ vnxt,
    const u32x4* __restrict__ wpk, int knext,
    u32x4 (&Bcur)[8], u32x4 (&Bnxt)[8])
{
    const int arow = lane & 15, ag = lane >> 4;

    // prefetch next step's B fragments (8 x dwordx4 from L2-resident packed W)
    load_b(wpk, knext, nt, lane, Bnxt);

    // epilogue x-hat values (LDS broadcast) — issue early
    float2 xv[2][4];
    #pragma unroll
    for (int mt = 0; mt < 2; ++mt)
        #pragma unroll
        for (int q = 0; q < 4; ++q)
            xv[mt][q] = *reinterpret_cast<const float2*>(
                &xh[(k * BT + mt * 16 + ag * 4 + q) * 2]);

    f32x4 acc[2][2];
    #pragma unroll
    for (int mt = 0; mt < 2; ++mt) {
        acc[mt][0] = f32x4{0.f, 0.f, 0.f, 0.f};
        acc[mt][1] = f32x4{0.f, 0.f, 0.f, 0.f};
    }

    #pragma unroll
    for (int kt = 0; kt < 4; ++kt) {
        half8 a[2];
        #pragma unroll
        for (int mt = 0; mt < 2; ++mt) {
            int row = mt * 16 + arow;
            int boff = (row * 256 + kt * 64 + ag * 16) ^ ((row & 7) << 4);
            a[mt] = *reinterpret_cast<const half8*>(
                reinterpret_cast<const char*>(vcur) + boff);
        }
        #pragma unroll
        for (int mt = 0; mt < 2; ++mt) {
            acc[mt][0] = __builtin_amdgcn_mfma_f32_16x16x32_f16(
                a[mt], __builtin_bit_cast(half8, Bcur[kt]), acc[mt][0], 0, 0, 0);
            acc[mt][1] = __builtin_amdgcn_mfma_f32_16x16x32_f16(
                a[mt], __builtin_bit_cast(half8, Bcur[4 + kt]), acc[mt][1], 0, 0, 0);
        }
    }

    // pin the prefetched B regs: forces their loads to be issued above and
    // completed here (under the MFMA cluster), and prevents sinking past the
    // barrier into the next step.
    #pragma unroll
    for (int j = 0; j < 8; ++j)
        asm volatile("" :: "v"(Bnxt[j][0]), "v"(Bnxt[j][1]),
                           "v"(Bnxt[j][2]), "v"(Bnxt[j][3]));

    // epilogue: vn = xh0*acc0 + xh1*acc1 (s already folded into xh), f16 store
    #pragma unroll
    for (int mt = 0; mt < 2; ++mt)
        #pragma unroll
        for (int q = 0; q < 4; ++q) {
            float vn = fmaf(xv[mt][q].x, acc[mt][0][q], xv[mt][q].y * acc[mt][1][q]);
            int row = mt * 16 + ag * 4 + q;      // D row = (lane>>4)*4+q
            int col = nt * 16 + arow;            // D col = lane&15
            int byte = (row * 256 + col * 2) ^ ((row & 7) << 4);
            *reinterpret_cast<unsigned short*>(
                reinterpret_cast<char*>(vnxt) + byte) = f16_bits(vn);
        }
    __syncthreads();
}

// ---- main: 512 blocks x 512 thr (8 waves = 8 N-tiles). Block = 32 batches.
// 2 blocks/CU -> two independent barrier domains overlap MFMA vs epilogue phases.
__global__ __launch_bounds__(512, 4) void mps_mfma(
    const float* __restrict__ x, const float* __restrict__ wf,
    const float* __restrict__ wl, const u32x4* __restrict__ wpk,
    float* __restrict__ out)
{
    __shared__ unsigned short vh[2][BT * 128];   // 8 KB each, ping-pong
    __shared__ float xh[NMID * BT * 2];          // 15.5 KB pre-scaled x
    const int tid = threadIdx.x;
    const int lane = tid & 63;
    const int nt = tid >> 6;
    const int bbase = blockIdx.x * BT;

    // prologue A: x-hat[k][row] = s * x(site k+1),  s = G_k * rsqrt(x0^2+x1^2)
    for (int idx = tid; idx < NMID * BT; idx += 512) {
        int k = idx >> 5, row = idx & 31;
        float2 xx = *reinterpret_cast<const float2*>(
            &x[(size_t)(bbase + row) * 128 + 2 + 2 * k]);
        float n2 = fmaf(xx.x, xx.x, fmaf(xx.y, xx.y, 1e-30f));
        float s = g_scale(k) * rsqrtf(n2);
        xh[idx * 2 + 0] = s * xx.x;
        xh[idx * 2 + 1] = s * xx.y;
    }

    // prologue B: v0 (only l<2 nonzero), normalized by s_init = 8*rsqrt(x0^2+x1^2)
    const float wf00 = wf[0], wf01 = wf[1], wf10 = wf[2], wf11 = wf[3];
    for (int idx = tid; idx < BT * 128; idx += 512) {
        int row = idx >> 7, l = idx & 127;
        float val = 0.f;
        if (l < 2) {
            float x0 = x[(size_t)(bbase + row) * 128 + 0];
            float x1 = x[(size_t)(bbase + row) * 128 + 1];
            float n2 = fmaf(x0, x0, fmaf(x1, x1, 1e-30f));
            float si = 8.0f * rsqrtf(n2);
            val = si * ((l == 0) ? (wf00 * x0 + wf10 * x1) : (wf01 * x0 + wf11 * x1));
        }
        int byte = (row * 256 + l * 2) ^ ((row & 7) << 4);
        *reinterpret_cast<unsigned short*>(
            reinterpret_cast<char*>(&vh[0][0]) + byte) = f16_bits(val);
    }
    __syncthreads();

    // ping-pong chain loop, unrolled by 2 with named B prefetch buffers
    u32x4 BA[8], BB[8];
    load_b(wpk, 0, nt, lane, BA);
    for (int kk = 0; kk < NMID; kk += 2) {
        do_step(kk,     xh, lane, nt, &vh[0][0], &vh[1][0], wpk, kk + 1, BA, BB);
        int k2n = (kk + 2 < NMID) ? kk + 2 : NMID - 1;
        do_step(kk + 1, xh, lane, nt, &vh[1][0], &vh[0][0], wpk, k2n, BB, BA);
    }

    // finale: recompute alpha = s_init * prod_k s_k from GLOBAL x (bitwise the
    // same rsqrtf factors as the prologue; no cross-thread communication), then
    // out[b] = (v0*(wl00*x0+wl01*x1) + v1*(wl10*x0+wl11*x1)) / alpha
    if (tid < BT) {
        int row = tid;
        const float* xb = &x[(size_t)(bbase + row) * 128];
        float n2i = fmaf(xb[0], xb[0], fmaf(xb[1], xb[1], 1e-30f));
        float alpha = 8.0f * rsqrtf(n2i);
        for (int k = 0; k < NMID; ++k) {
            float2 xx = *reinterpret_cast<const float2*>(&xb[2 + 2 * k]);
            float n2 = fmaf(xx.x, xx.x, fmaf(xx.y, xx.y, 1e-30f));
            alpha *= g_scale(k) * rsqrtf(n2);
        }
        int boff = (row * 256) ^ ((row & 7) << 4);
        unsigned hw = *reinterpret_cast<unsigned*>(
            reinterpret_cast<char*>(&vh[0][0]) + boff);
        float v0 = (float)__builtin_bit_cast(_Float16, (unsigned short)(hw & 0xffffu));
        float v1 = (float)__builtin_bit_cast(_Float16, (unsigned short)(hw >> 16));
        float x0 = xb[126], x1 = xb[127];
        float val = v0 * (wl[0] * x0 + wl[1] * x1)
                  + v1 * (wl[2] * x0 + wl[3] * x1);
        out[bbase + row] = val / alpha;
    }
}

// ---------------- fallback fp32 vector kernel (used only if ws too small) ----
#define FBT 32
__global__ __launch_bounds__(256, 2) void mps_chain_kernel(
    const float* __restrict__ x, const float* __restrict__ wf,
    const float* __restrict__ wm, const float* __restrict__ wl,
    float* __restrict__ out)
{
    __shared__ float vbuf[2][128][FBT];
    __shared__ float xs_lds[FBT][126];
    const int tid = threadIdx.x;
    const int rg = tid >> 3, bg = tid & 7;
    const int r0 = rg * 4, b0 = bg * 4;
    const int bbase = blockIdx.x * FBT;
    for (int idx = tid; idx < FBT * 126; idx += 256) {
        int b = idx / 126, j = idx % 126;
        xs_lds[b][j] = x[(size_t)(bbase + b) * 128 + 2 + j];
    }
    const float wf00 = wf[0], wf01 = wf[1], wf10 = wf[2], wf11 = wf[3];
    for (int idx = tid; idx < 128 * FBT; idx += 256) {
        int l = idx / FBT, b = idx % FBT;
        float val = 0.0f;
        if (l < 2) {
            float x0 = x[(size_t)(bbase + b) * 128 + 0];
            float x1 = x[(size_t)(bbase + b) * 128 + 1];
            val = (l == 0) ? (wf00 * x0 + wf10 * x1) : (wf01 * x0 + wf11 * x1);
        }
        vbuf[0][l][b] = val;
    }
    __syncthreads();
    int cur = 0;
    for (int k = 0; k < NMID; ++k) {
        const float* __restrict__ Wk = wm + (size_t)k * (2 * 128 * 128);
        float acc0[4][4], acc1[4][4];
        #pragma unroll
        for (int bb = 0; bb < 4; ++bb)
            #pragma unroll
            for (int rr = 0; rr < 4; ++rr) { acc0[bb][rr] = 0.0f; acc1[bb][rr] = 0.0f; }
        #pragma unroll 4
        for (int l = 0; l < 128; ++l) {
            float4 vv = *reinterpret_cast<const float4*>(&vbuf[cur][l][b0]);
            float4 w0 = *reinterpret_cast<const float4*>(&Wk[(size_t)(2 * l) * 128 + r0]);
            float4 w1 = *reinterpret_cast<const float4*>(&Wk[(size_t)(2 * l + 1) * 128 + r0]);
            float va[4] = { vv.x, vv.y, vv.z, vv.w };
            float w0a[4] = { w0.x, w0.y, w0.z, w0.w };
            float w1a[4] = { w1.x, w1.y, w1.z, w1.w };
            #pragma unroll
            for (int bb = 0; bb < 4; ++bb)
                #pragma unroll
                for (int rr = 0; rr < 4; ++rr) {
                    acc0[bb][rr] = fmaf(va[bb], w0a[rr], acc0[bb][rr]);
                    acc1[bb][rr] = fmaf(va[bb], w1a[rr], acc1[bb][rr]);
                }
        }
        const int nxt = cur ^ 1;
        float vn[4][4];
        #pragma unroll
        for (int bb = 0; bb < 4; ++bb) {
            float xx0 = xs_lds[b0 + bb][2 * k + 0];
            float xx1 = xs_lds[b0 + bb][2 * k + 1];
            #pragma unroll
            for (int rr = 0; rr < 4; ++rr)
                vn[bb][rr] = xx0 * acc0[bb][rr] + xx1 * acc1[bb][rr];
        }
        #pragma unroll
        for (int rr = 0; rr < 4; ++rr) {
            float4 wv = make_float4(vn[0][rr], vn[1][rr], vn[2][rr], vn[3][rr]);
            *reinterpret_cast<float4*>(&vbuf[nxt][r0 + rr][b0]) = wv;
        }
        cur = nxt;
        __syncthreads();
    }
    if (rg == 0) {
        const float wl00 = wl[0], wl01 = wl[1], wl10 = wl[2], wl11 = wl[3];
        #pragma unroll
        for (int bb = 0; bb < 4; ++bb) {
            int b = b0 + bb;
            float v0 = vbuf[cur][0][b];
            float v1 = vbuf[cur][1][b];
            float xx0 = xs_lds[b][124];
            float xx1 = xs_lds[b][125];
            out[bbase + b] = v0 * (wl00 * xx0 + wl01 * xx1)
                           + v1 * (wl10 * xx0 + wl11 * xx1);
        }
    }
}

extern "C" void kernel_launch(void* const* d_in, const int* in_sizes, int n_in,
                              void* d_out, int out_size, void* d_ws, size_t ws_size,
                              hipStream_t stream) {
    const float* x  = (const float*)d_in[0];
    const float* wf = (const float*)d_in[1];
    const float* wm = (const float*)d_in[2];
    const float* wl = (const float*)d_in[3];
    float* out = (float*)d_out;

    const size_t ws_needed = (size_t)124 * 8 * 4 * 64 * 16;  // 4.06 MB packed W (f16)
    if (ws_size >= ws_needed) {
        u32x4* wpk = (u32x4*)d_ws;
        hipLaunchKernelGGL(mps_pack_w, dim3(992), dim3(256), 0, stream, wm, wpk);
        hipLaunchKernelGGL(mps_mfma, dim3(NBATCH / BT), dim3(512), 0, stream,
                           x, wf, wl, wpk, out);
    } else {
        hipLaunchKernelGGL(mps_chain_kernel, dim3(NBATCH / FBT), dim3(256), 0, stream,
                           x, wf, wm, wl, out);
    }
}